// Round 1
// baseline (1694.180 us; speedup 1.0000x reference)
//
#include <hip/hip_runtime.h>

// Acoustic stress-velocity FD propagator, MI355X.
// Strategy: 1 fused kernel per time step; double-buffered state; redundant
// neighbor-velocity recomputation (no intra-kernel sync needed); receiver
// gather shifted by one step into the next kernel.

#define NXc 256
#define NZc 256
#define NTc 400
#define NSc 4
#define NRc 128

__device__ __constant__ float kDX = 10.0f;
__device__ __constant__ float kDZ = 10.0f;

constexpr float DT_H = 0.001f;
constexpr int NXZ = NXc * NZc;

__global__ __launch_bounds__(256) void coef_kernel(
    const float* __restrict__ vp, const float* __restrict__ rho,
    const float* __restrict__ damp,
    float* __restrict__ fac, float* __restrict__ binv, float* __restrict__ dtk)
{
    int j = blockIdx.x * 256 + threadIdx.x;
    if (j >= NXZ) return;
    float r = rho[j], v = vp[j];
    fac[j]  = 1.0f - DT_H * damp[j];
    binv[j] = DT_H / r;
    dtk[j]  = DT_H * r * v * v;
}

__global__ __launch_bounds__(256) void step_kernel(
    const float* __restrict__ p_old, const float* __restrict__ vx_old,
    const float* __restrict__ vz_old,
    float* __restrict__ p_new, float* __restrict__ vx_new,
    float* __restrict__ vz_new,
    const float* __restrict__ fac, const float* __restrict__ binv,
    const float* __restrict__ dtk,
    const float* __restrict__ wavelet,
    const int* __restrict__ src_x, const int* __restrict__ src_z,
    const int* __restrict__ rcv_x, const int* __restrict__ rcv_z,
    float* __restrict__ out, int t)
{
    int flat = blockIdx.x * 256 + threadIdx.x;

    // Record previous step's pressure (state after step t-1) at receivers.
    if (t > 0 && flat < NSc * NRc) {
        int s2 = flat / NRc, r = flat % NRc;
        out[(s2 * NTc + (t - 1)) * NRc + r] =
            p_old[s2 * NXZ + rcv_x[r] * NZc + rcv_z[r]];
    }

    int k = flat & (NZc - 1);
    int i = (flat >> 8) & (NXc - 1);
    int s = flat >> 16;
    int c = flat;              // s*NXZ + i*NZ + k
    int g = i * NZc + k;       // coefficient index (shared across shots)

    const float inv_dx = 1.0f / 10.0f;
    const float inv_dz = 1.0f / 10.0f;

    float pc = p_old[c];
    float fc = fac[g], bc = binv[g];

    // vx_new at (i,k): forward-diff of p in x, zero-padded at i=NX-1.
    float vxc;
    if (i < NXc - 1) vxc = fc * vx_old[c] - bc * (p_old[c + NZc] - pc) * inv_dx;
    else             vxc = fc * vx_old[c];

    // vz_new at (i,k): forward-diff of p in z, zero-padded at k=NZ-1.
    float vzc;
    if (k < NZc - 1) vzc = fc * vz_old[c] - bc * (p_old[c + 1] - pc) * inv_dz;
    else             vzc = fc * vz_old[c];

    // Divergence with backward diffs, zero-padded at i=0 / k=0.
    float div = 0.0f;
    if (i > 0) {
        float fm = fac[g - NZc], bm = binv[g - NZc];
        // vx_new at (i-1,k), recomputed identically to its owner thread.
        float vxm = fm * vx_old[c - NZc] - bm * (pc - p_old[c - NZc]) * inv_dx;
        div += (vxc - vxm) * inv_dx;
    }
    if (k > 0) {
        float fm = fac[g - 1], bm = binv[g - 1];
        float vzm = fm * vz_old[c - 1] - bm * (pc - p_old[c - 1]) * inv_dz;
        div += (vzc - vzm) * inv_dz;
    }

    float pn = fc * pc - dtk[g] * div;

    // Source injection (one cell per shot).
    if (i == src_x[s] && k == src_z[s]) {
        pn += wavelet[s * NTc + t] * (DT_H / (10.0f * 10.0f));
    }

    p_new[c]  = pn;
    vx_new[c] = vxc;
    vz_new[c] = vzc;
}

__global__ __launch_bounds__(256) void final_gather(
    const float* __restrict__ p,
    const int* __restrict__ rcv_x, const int* __restrict__ rcv_z,
    float* __restrict__ out)
{
    int flat = blockIdx.x * 256 + threadIdx.x;
    if (flat >= NSc * NRc) return;
    int s = flat / NRc, r = flat % NRc;
    out[(s * NTc + (NTc - 1)) * NRc + r] =
        p[s * NXZ + rcv_x[r] * NZc + rcv_z[r]];
}

extern "C" void kernel_launch(void* const* d_in, const int* in_sizes, int n_in,
                              void* d_out, int out_size, void* d_ws, size_t ws_size,
                              hipStream_t stream)
{
    const float* vp      = (const float*)d_in[0];
    const float* rho     = (const float*)d_in[1];
    const float* damp    = (const float*)d_in[2];
    const float* wavelet = (const float*)d_in[3];
    const int*   src_x   = (const int*)d_in[4];
    const int*   src_z   = (const int*)d_in[5];
    const int*   rcv_x   = (const int*)d_in[6];
    const int*   rcv_z   = (const int*)d_in[7];
    float* out = (float*)d_out;
    float* ws  = (float*)d_ws;

    const size_t F = (size_t)NSc * NXZ;  // one field, all shots
    float* p0   = ws;
    float* vx0  = p0  + F;
    float* vz0  = vx0 + F;
    float* p1   = vz0 + F;
    float* vx1  = p1  + F;
    float* vz1  = vx1 + F;
    float* fac  = vz1 + F;
    float* binv = fac  + NXZ;
    float* dtk  = binv + NXZ;

    // Zero initial state (p0, vx0, vz0 are contiguous). Done every call:
    // ws is poisoned once and never re-poisoned between timed replays.
    hipMemsetAsync(p0, 0, 3 * F * sizeof(float), stream);

    coef_kernel<<<NXZ / 256, 256, 0, stream>>>(vp, rho, damp, fac, binv, dtk);

    float* bufA[3] = {p0, vx0, vz0};
    float* bufB[3] = {p1, vx1, vz1};
    const int nblk = (int)(F / 256);  // 1024 blocks

    for (int t = 0; t < NTc; ++t) {
        float** rd = (t & 1) ? bufB : bufA;
        float** wr = (t & 1) ? bufA : bufB;
        step_kernel<<<nblk, 256, 0, stream>>>(
            rd[0], rd[1], rd[2], wr[0], wr[1], wr[2],
            fac, binv, dtk, wavelet, src_x, src_z, rcv_x, rcv_z, out, t);
    }

    // After t=399 (odd), final state is in bufA (p0).
    final_gather<<<2, 256, 0, stream>>>(p0, rcv_x, rcv_z, out);
}

// Round 2
// 1091.170 us; speedup vs baseline: 1.5526x; 1.5526x over previous
//
#include <hip/hip_runtime.h>

// Acoustic stress-velocity FD propagator, MI355X.
// Temporal blocking: each launch advances T=8 time steps. Each block owns a
// 32x32 output tile (per shot), loads a 48x48 halo'd region of {p,vx,vz} and
// coefficients into LDS, runs 8 in-place steps with a shrinking valid region
// (trapezoid), injects the source, records receivers, stores the central tile.
// No inter-block communication within a launch -> 400 launches become 50.

#define NXc 256
#define NZc 256
#define NTc 400
#define NSc 4
#define NRc 128

#define TSTEPS 8
#define Bt 32               // output tile edge
#define Rt (Bt + 2*TSTEPS)  // 48: loaded region edge
#define RC (Rt*Rt)          // 2304
#define BT 512              // threads per block

constexpr float DT_H   = 0.001f;
constexpr float INV_D  = 0.1f;                    // 1/DX = 1/DZ
constexpr float SRC_AMP = 0.001f / (10.0f*10.0f); // DT/(DX*DZ)
constexpr int   NXZ = NXc * NZc;

__global__ __launch_bounds__(256) void coef_kernel(
    const float* __restrict__ vp, const float* __restrict__ rho,
    const float* __restrict__ damp,
    float* __restrict__ fac, float* __restrict__ binv, float* __restrict__ dtk)
{
    int j = blockIdx.x * 256 + threadIdx.x;
    if (j >= NXZ) return;
    float r = rho[j], v = vp[j];
    fac[j]  = 1.0f - DT_H * damp[j];
    binv[j] = DT_H / r;
    dtk[j]  = DT_H * r * v * v;
}

__global__ __launch_bounds__(BT) void tstep_kernel(
    const float* __restrict__ p_in,  const float* __restrict__ vx_in,
    const float* __restrict__ vz_in,
    float* __restrict__ p_out, float* __restrict__ vx_out,
    float* __restrict__ vz_out,
    const float* __restrict__ fac_g, const float* __restrict__ binv_g,
    const float* __restrict__ dtk_g,
    const float* __restrict__ wavelet,
    const int* __restrict__ src_x, const int* __restrict__ src_z,
    const int* __restrict__ rcv_x, const int* __restrict__ rcv_z,
    float* __restrict__ out, int t0)
{
    __shared__ float sp[RC], svx[RC], svz[RC], sfac[RC], sbinv[RC], sdtk[RC];

    const int tid = threadIdx.x;
    const int bid = blockIdx.x;
    const int s    = bid >> 6;        // shot
    const int tile = bid & 63;
    const int tx = tile >> 3, tz = tile & 7;
    const int gx0 = tx * Bt - TSTEPS; // region origin (may be out of domain)
    const int gz0 = tz * Bt - TSTEPS;

    // ---- load region (out-of-domain -> 0; zero coefs keep ghosts at 0) ----
    for (int j = tid; j < RC; j += BT) {
        int li = j / Rt, lk = j - li * Rt;
        int gi = gx0 + li, gk = gz0 + lk;
        bool in = ((unsigned)gi < (unsigned)NXc) && ((unsigned)gk < (unsigned)NZc);
        int g = gi * NZc + gk;
        int c = s * NXZ + g;
        sp[j]   = in ? p_in[c]   : 0.0f;
        svx[j]  = in ? vx_in[c]  : 0.0f;
        svz[j]  = in ? vz_in[c]  : 0.0f;
        sfac[j]  = in ? fac_g[g]  : 0.0f;
        sbinv[j] = in ? binv_g[g] : 0.0f;
        sdtk[j]  = in ? dtk_g[g]  : 0.0f;
    }

    const int sx = src_x[s], sz = src_z[s];
    int rx = -1, rz = -1;
    if (tid < NRc) { rx = rcv_x[tid]; rz = rcv_z[tid]; }
    __syncthreads();

    for (int tau = 0; tau < TSTEPS; ++tau) {
        const int t = t0 + tau;

        // ---- velocity phase: valid square [tau, Rt-1-tau) ----
        {
            const int lo = tau, hi = Rt - 1 - tau;
            for (int j = tid; j < RC; j += BT) {
                int li = j / Rt, lk = j - li * Rt;
                if (li < lo || li >= hi || lk < lo || lk >= hi) continue;
                int gi = gx0 + li, gk = gz0 + lk;
                float pc = sp[j];
                float fc = sfac[j], bc = sbinv[j];
                float dpx = (gi == NXc - 1) ? 0.0f : (sp[j + Rt] - pc);
                float dpz = (gk == NZc - 1) ? 0.0f : (sp[j + 1]  - pc);
                svx[j] = fc * svx[j] - bc * (dpx * INV_D);
                svz[j] = fc * svz[j] - bc * (dpz * INV_D);
            }
        }
        __syncthreads();

        // ---- pressure phase: valid square [tau+1, Rt-1-tau) ----
        {
            const float wv = wavelet[s * NTc + t] * SRC_AMP; // uniform s_load
            const int lo = tau + 1, hi = Rt - 1 - tau;
            for (int j = tid; j < RC; j += BT) {
                int li = j / Rt, lk = j - li * Rt;
                if (li < lo || li >= hi || lk < lo || lk >= hi) continue;
                float div = (svx[j] - svx[j - Rt]) * INV_D
                          + (svz[j] - svz[j - 1]) * INV_D;
                float pn = sfac[j] * sp[j] - sdtk[j] * div;
                int gi = gx0 + li, gk = gz0 + lk;
                if (gi == sx && gk == sz) pn += wv;
                sp[j] = pn;
            }
        }
        __syncthreads();

        // ---- receivers: owner tile records p after this step ----
        if (tid < NRc && rx >= tx * Bt && rx < tx * Bt + Bt
                      && rz >= tz * Bt && rz < tz * Bt + Bt) {
            out[(s * NTc + t) * NRc + tid] = sp[(rx - gx0) * Rt + (rz - gz0)];
        }
        // (record reads sp; next velocity phase writes only svx/svz -> safe)
    }

    // ---- store central 32x32 of all three fields ----
    for (int j = tid; j < Bt * Bt; j += BT) {
        int li = TSTEPS + (j >> 5), lk = TSTEPS + (j & 31);
        int gi = gx0 + li, gk = gz0 + lk;
        int c = s * NXZ + gi * NZc + gk;
        int jj = li * Rt + lk;
        p_out[c]  = sp[jj];
        vx_out[c] = svx[jj];
        vz_out[c] = svz[jj];
    }
}

extern "C" void kernel_launch(void* const* d_in, const int* in_sizes, int n_in,
                              void* d_out, int out_size, void* d_ws, size_t ws_size,
                              hipStream_t stream)
{
    const float* vp      = (const float*)d_in[0];
    const float* rho     = (const float*)d_in[1];
    const float* damp    = (const float*)d_in[2];
    const float* wavelet = (const float*)d_in[3];
    const int*   src_x   = (const int*)d_in[4];
    const int*   src_z   = (const int*)d_in[5];
    const int*   rcv_x   = (const int*)d_in[6];
    const int*   rcv_z   = (const int*)d_in[7];
    float* out = (float*)d_out;
    float* ws  = (float*)d_ws;

    const size_t F = (size_t)NSc * NXZ;
    float* p0   = ws;
    float* vx0  = p0  + F;
    float* vz0  = vx0 + F;
    float* p1   = vz0 + F;
    float* vx1  = p1  + F;
    float* vz1  = vx1 + F;
    float* fac  = vz1 + F;
    float* binv = fac  + NXZ;
    float* dtk  = binv + NXZ;

    // Zero initial state every call (ws poisoned once, never re-poisoned).
    hipMemsetAsync(p0, 0, 3 * F * sizeof(float), stream);

    coef_kernel<<<NXZ / 256, 256, 0, stream>>>(vp, rho, damp, fac, binv, dtk);

    const int nblk = NSc * (NXc / Bt) * (NZc / Bt); // 256
    const int nlaunch = NTc / TSTEPS;               // 50

    for (int l = 0; l < nlaunch; ++l) {
        const float* pi  = (l & 1) ? p1  : p0;
        const float* vxi = (l & 1) ? vx1 : vx0;
        const float* vzi = (l & 1) ? vz1 : vz0;
        float* po  = (l & 1) ? p0  : p1;
        float* vxo = (l & 1) ? vx0 : vx1;
        float* vzo = (l & 1) ? vz0 : vz1;
        tstep_kernel<<<nblk, BT, 0, stream>>>(
            pi, vxi, vzi, po, vxo, vzo,
            fac, binv, dtk, wavelet, src_x, src_z, rcv_x, rcv_z, out,
            l * TSTEPS);
    }
}

// Round 3
// 584.885 us; speedup vs baseline: 2.8966x; 1.8656x over previous
//
#include <hip/hip_runtime.h>

// Acoustic stress-velocity FD propagator, MI355X — temporal blocking v2.
// 16x16 output tile per block, 32x32 region (halo=TSTEPS=8), 256 threads,
// 4 cells/thread. Own state + all coefficients in REGISTERS; LDS (3 arrays,
// 12.75 KB) only for neighbor exchange. No validity checks: garbage ring is
// quarantined by the trapezoid (central 16x16 exact after 8 steps).
// 50 launches total; first launch zero-inits in-kernel (no memset).

#define NXc 256
#define NZc 256
#define NTc 400
#define NSc 4
#define NRc 128

#define TS 8
#define Bt 16
#define Rt 32               // Bt + 2*TS
#define STRIDE 32
#define CELLS (Rt*Rt)       // 1024
#define LSZ ((Rt+2)*STRIDE) // 1088 (one pad row above/below)
#define BT 256
#define CPT (CELLS/BT)      // 4

constexpr float DT_H    = 0.001f;
constexpr float INV_D   = 0.1f;            // 1/DX = 1/DZ
constexpr float SRC_AMP = 0.001f * 0.01f;  // DT/(DX*DZ)
constexpr int   NXZ     = NXc * NZc;

__global__ __launch_bounds__(BT) void tstep_kernel(
    const float* __restrict__ p_in,  const float* __restrict__ vx_in,
    const float* __restrict__ vz_in,
    float* __restrict__ p_out, float* __restrict__ vx_out,
    float* __restrict__ vz_out,
    const float* __restrict__ vp, const float* __restrict__ rho,
    const float* __restrict__ damp,
    const float* __restrict__ wavelet,
    const int* __restrict__ src_x, const int* __restrict__ src_z,
    const int* __restrict__ rcv_x, const int* __restrict__ rcv_z,
    float* __restrict__ out, int t0, int zinit)
{
    __shared__ float sp[LSZ], svx[LSZ], svz[LSZ];

    const int tid  = threadIdx.x;
    const int bid  = blockIdx.x;
    const int s    = bid >> 8;        // 256 tiles per shot
    const int tile = bid & 255;
    const int tx = tile >> 4, tz = tile & 15;
    const int gx0 = tx * Bt - TS;     // region origin (may be out of domain)
    const int gz0 = tz * Bt - TS;

    const int sx = src_x[s], sz = src_z[s];

    // Per-cell time-invariant coefficients + state, all in registers.
    float fr[CPT], bxr[CPT], bzr[CPT], dkxr[CPT], dkzr[CPT], sfr[CPT];
    float pr[CPT], vxr[CPT], vzr[CPT];

#pragma unroll
    for (int k = 0; k < CPT; ++k) {
        int cc = tid + k * BT;
        int li = cc >> 5, lk = cc & 31;
        int gi = gx0 + li, gk = gz0 + lk;
        bool in = ((unsigned)gi < (unsigned)NXc) && ((unsigned)gk < (unsigned)NZc);
        int g = gi * NZc + gk;
        int c = s * NXZ + g;

        float pv = 0.f, vxv = 0.f, vzv = 0.f;
        if (in && !zinit) { pv = p_in[c]; vxv = vx_in[c]; vzv = vz_in[c]; }

        float fv = 0.f, bx = 0.f, bz = 0.f, dkx = 0.f, dkz = 0.f, sf = 0.f;
        if (in) {
            float rv = rho[g], vv = vp[g];
            fv = 1.0f - DT_H * damp[g];
            float bi = DT_H / rv * INV_D;
            bx = (gi == NXc - 1) ? 0.f : bi;   // _dxf zero-pad at last row
            bz = (gk == NZc - 1) ? 0.f : bi;   // _dzf zero-pad at last col
            float dk = DT_H * rv * vv * vv * INV_D;
            dkx = (gi == 0) ? 0.f : dk;        // _dxb zero-pad at first row
            dkz = (gk == 0) ? 0.f : dk;        // _dzb zero-pad at first col
            if (gi == sx && gk == sz) sf = SRC_AMP;
        }
        fr[k] = fv; bxr[k] = bx; bzr[k] = bz;
        dkxr[k] = dkx; dkzr[k] = dkz; sfr[k] = sf;
        pr[k] = pv; vxr[k] = vxv; vzr[k] = vzv;

        int j = STRIDE + cc;
        sp[j] = pv; svx[j] = vxv; svz[j] = vzv;
    }
    // Zero the pad rows (keeps out-of-domain cells exactly 0, no NaN risk).
    if (tid < STRIDE) {
        sp[tid] = 0.f; svx[tid] = 0.f; svz[tid] = 0.f;
        sp[LSZ - STRIDE + tid] = 0.f;
        svx[LSZ - STRIDE + tid] = 0.f;
        svz[LSZ - STRIDE + tid] = 0.f;
    }
    int rxv = 0, rzv = 0;
    if (tid < NRc) { rxv = rcv_x[tid]; rzv = rcv_z[tid]; }
    __syncthreads();

    const int jb = STRIDE + tid;

    for (int tau = 0; tau < TS; ++tau) {
        // ---- velocity phase (writes svx/svz, reads sp) ----
#pragma unroll
        for (int k = 0; k < CPT; ++k) {
            int j = jb + k * BT;
            float pc  = pr[k];
            float dpx = sp[j + STRIDE] - pc;
            float dpz = sp[j + 1] - pc;
            float nvx = fr[k] * vxr[k] - bxr[k] * dpx;
            float nvz = fr[k] * vzr[k] - bzr[k] * dpz;
            vxr[k] = nvx; vzr[k] = nvz;
            svx[j] = nvx; svz[j] = nvz;
        }
        __syncthreads();

        const float wv = wavelet[s * NTc + t0 + tau];

        // ---- pressure phase (writes sp, reads svx/svz) ----
#pragma unroll
        for (int k = 0; k < CPT; ++k) {
            int j = jb + k * BT;
            float dx = vxr[k] - svx[j - STRIDE];
            float dz = vzr[k] - svz[j - 1];
            float pn = fr[k] * pr[k] - dkxr[k] * dx - dkzr[k] * dz
                     + sfr[k] * wv;
            pr[k] = pn;
            sp[j] = pn;
        }
        __syncthreads();

        // ---- receivers: owner tile records (reads sp; next phase writes
        //      only svx/svz, so concurrent with next velocity phase is safe)
        if (tid < NRc) {
            int lrx = rxv - gx0 - TS, lrz = rzv - gz0 - TS;
            if ((unsigned)lrx < (unsigned)Bt && (unsigned)lrz < (unsigned)Bt) {
                out[(s * NTc + t0 + tau) * NRc + tid] =
                    sp[STRIDE + (rxv - gx0) * STRIDE + (rzv - gz0)];
            }
        }
    }

    // ---- store central 16x16 straight from registers ----
    // k=1: li in [8,16); k=2: li in [16,24) — always central in x.
#pragma unroll
    for (int k = 1; k <= 2; ++k) {
        int cc = tid + k * BT;
        int li = cc >> 5, lk = cc & 31;
        if (lk >= TS && lk < TS + Bt) {
            int gi = gx0 + li, gk = gz0 + lk;
            int c = s * NXZ + gi * NZc + gk;
            p_out[c] = pr[k]; vx_out[c] = vxr[k]; vz_out[c] = vzr[k];
        }
    }
}

extern "C" void kernel_launch(void* const* d_in, const int* in_sizes, int n_in,
                              void* d_out, int out_size, void* d_ws, size_t ws_size,
                              hipStream_t stream)
{
    const float* vp      = (const float*)d_in[0];
    const float* rho     = (const float*)d_in[1];
    const float* damp    = (const float*)d_in[2];
    const float* wavelet = (const float*)d_in[3];
    const int*   src_x   = (const int*)d_in[4];
    const int*   src_z   = (const int*)d_in[5];
    const int*   rcv_x   = (const int*)d_in[6];
    const int*   rcv_z   = (const int*)d_in[7];
    float* out = (float*)d_out;
    float* ws  = (float*)d_ws;

    const size_t F = (size_t)NSc * NXZ;
    float* pA  = ws;
    float* vxA = pA  + F;
    float* vzA = vxA + F;
    float* pB  = vzA + F;
    float* vxB = pB  + F;
    float* vzB = vxB + F;

    const int nblk = NSc * (NXc / Bt) * (NZc / Bt);  // 1024
    const int nlaunch = NTc / TS;                    // 50

    for (int l = 0; l < nlaunch; ++l) {
        const float* pi  = (l & 1) ? pB  : pA;
        const float* vxi = (l & 1) ? vxB : vxA;
        const float* vzi = (l & 1) ? vzB : vzA;
        float* po  = (l & 1) ? pA  : pB;
        float* vxo = (l & 1) ? vxA : vxB;
        float* vzo = (l & 1) ? vzA : vzB;
        // l==0: zero-init in-kernel (input buffers are ignored).
        tstep_kernel<<<nblk, BT, 0, stream>>>(
            pi, vxi, vzi, po, vxo, vzo,
            vp, rho, damp, wavelet, src_x, src_z, rcv_x, rcv_z, out,
            l * TS, (l == 0) ? 1 : 0);
    }
}

// Round 4
// 487.928 us; speedup vs baseline: 3.4722x; 1.1987x over previous
//
#include <hip/hip_runtime.h>

// Acoustic stress-velocity FD propagator, MI355X — temporal blocking v3.
// 16x16 output tile, 32x32 region (halo=TS=8), 256 threads, each thread owns
// a 1x4 z-strip (registers). LDS holds only p and vx (for x-neighbor
// exchange, b128 ops); z-neighbors via registers + one __shfl per phase.
// DS-pipe insts per wave per step: 2x b128 read + 2x b128 write + 2 bpermute
// (~66 cyc) vs 28x b32 (~163 cyc) in v2.

#define NXc 256
#define NZc 256
#define NTc 400
#define NSc 4
#define NRc 128

#define TS 8
#define Bt 16
#define Rt 32                 // region edge
#define LROW 32               // LDS row stride (floats)
#define LSZ ((Rt + 2) * LROW) // 1088: one pad row above/below
#define BT 256

constexpr float DT_H    = 0.001f;
constexpr float INV_D   = 0.1f;            // 1/DX = 1/DZ
constexpr float SRC_AMP = 0.001f * 0.01f;  // DT/(DX*DZ)
constexpr int   NXZ     = NXc * NZc;

__global__ __launch_bounds__(BT) void tstep_kernel(
    const float* __restrict__ p_in,  const float* __restrict__ vx_in,
    const float* __restrict__ vz_in,
    float* __restrict__ p_out, float* __restrict__ vx_out,
    float* __restrict__ vz_out,
    const float* __restrict__ vp, const float* __restrict__ rho,
    const float* __restrict__ damp,
    const float* __restrict__ wavelet,
    const int* __restrict__ src_x, const int* __restrict__ src_z,
    const int* __restrict__ rcv_x, const int* __restrict__ rcv_z,
    float* __restrict__ out, int t0, int zinit)
{
    __shared__ float sp[LSZ], svx[LSZ];

    const int tid  = threadIdx.x;
    const int bid  = blockIdx.x;
    const int s    = bid >> 8;        // 256 tiles per shot
    const int tile = bid & 255;
    const int tx = tile >> 4, tz = tile & 15;
    const int gx0 = tx * Bt - TS;
    const int gz0 = tz * Bt - TS;

    const int li  = tid >> 3;              // region row of this thread
    const int lk0 = (tid & 7) * 4;         // first col of strip
    const int gi  = gx0 + li;
    const int gk0 = gz0 + lk0;
    const bool in = ((unsigned)gi < (unsigned)NXc) &&
                    ((unsigned)gk0 < (unsigned)NZc);   // strip fully in/out
    const int g4 = gi * NZc + gk0;         // global index of strip start
    const int c4 = s * NXZ + g4;

    const int sx = src_x[s], sz = src_z[s];

    // ---- per-cell time-invariant coefficients + state (registers) ----
    float pr[4]  = {0, 0, 0, 0};
    float vxr[4] = {0, 0, 0, 0};
    float vzr[4] = {0, 0, 0, 0};
    float fr[4], bxr[4], bzr[4], dkxr[4], dkzr[4], sfr[4];

    if (in) {
        if (!zinit) {
            float4 p4  = *(const float4*)(p_in  + c4);
            float4 vx4 = *(const float4*)(vx_in + c4);
            float4 vz4 = *(const float4*)(vz_in + c4);
            pr[0]=p4.x; pr[1]=p4.y; pr[2]=p4.z; pr[3]=p4.w;
            vxr[0]=vx4.x; vxr[1]=vx4.y; vxr[2]=vx4.z; vxr[3]=vx4.w;
            vzr[0]=vz4.x; vzr[1]=vz4.y; vzr[2]=vz4.z; vzr[3]=vz4.w;
        }
        float4 r4 = *(const float4*)(rho  + g4);
        float4 v4 = *(const float4*)(vp   + g4);
        float4 d4 = *(const float4*)(damp + g4);
        float rv[4] = {r4.x, r4.y, r4.z, r4.w};
        float vv[4] = {v4.x, v4.y, v4.z, v4.w};
        float dv[4] = {d4.x, d4.y, d4.z, d4.w};
#pragma unroll
        for (int k = 0; k < 4; ++k) {
            int gk = gk0 + k;
            fr[k] = 1.0f - DT_H * dv[k];
            float bi = DT_H / rv[k] * INV_D;
            bxr[k] = (gi == NXc - 1) ? 0.f : bi;   // _dxf zero-pad
            bzr[k] = (gk == NZc - 1) ? 0.f : bi;   // _dzf zero-pad
            float dk = DT_H * rv[k] * vv[k] * vv[k] * INV_D;
            dkxr[k] = (gi == 0) ? 0.f : dk;        // _dxb zero-pad
            dkzr[k] = (gk == 0) ? 0.f : dk;        // _dzb zero-pad
            sfr[k]  = (gi == sx && gk == sz) ? SRC_AMP : 0.f;
        }
    } else {
#pragma unroll
        for (int k = 0; k < 4; ++k) {
            fr[k]=0.f; bxr[k]=0.f; bzr[k]=0.f;
            dkxr[k]=0.f; dkzr[k]=0.f; sfr[k]=0.f;
        }
    }

    const int jb = LROW + tid * 4;   // LDS index of strip (pad row on top)
    *(float4*)&sp[jb] = make_float4(pr[0], pr[1], pr[2], pr[3]);

    // Zero pad rows (top for svx row-1 reads, bottom for sp row+1 reads).
    if (tid < LROW) {
        sp[tid] = 0.f; svx[tid] = 0.f;
        sp[LSZ - LROW + tid] = 0.f; svx[LSZ - LROW + tid] = 0.f;
    }
    int rxv = 0, rzv = 0;
    if (tid < NRc) { rxv = rcv_x[tid]; rzv = rcv_z[tid]; }
    const bool rown = (tid < NRc) &&
        ((unsigned)(rxv - gx0 - TS) < (unsigned)Bt) &&
        ((unsigned)(rzv - gz0 - TS) < (unsigned)Bt);
    const int rj = LROW + (rxv - gx0) * LROW + (rzv - gz0);
    __syncthreads();

    for (int tau = 0; tau < TS; ++tau) {
        // ---- velocity phase: reads sp, writes svx (vz stays in regs) ----
        float4 pn4 = *(const float4*)&sp[jb + LROW];  // row+1 strip
        float pzn  = __shfl_down(pr[0], 1, 64);       // next strip's p[0]
        float pnx[4] = {pn4.x, pn4.y, pn4.z, pn4.w};
        float pz1[4] = {pr[1], pr[2], pr[3], pzn};
#pragma unroll
        for (int k = 0; k < 4; ++k) {
            vxr[k] = fr[k] * vxr[k] - bxr[k] * (pnx[k] - pr[k]);
            vzr[k] = fr[k] * vzr[k] - bzr[k] * (pz1[k] - pr[k]);
        }
        *(float4*)&svx[jb] = make_float4(vxr[0], vxr[1], vxr[2], vxr[3]);
        __syncthreads();

        const float wv = wavelet[s * NTc + t0 + tau];

        // ---- pressure phase: reads svx, writes sp ----
        float4 vm4 = *(const float4*)&svx[jb - LROW]; // row-1 strip (new vx)
        float vzp  = __shfl_up(vzr[3], 1, 64);        // prev strip's vz[3]
        float vxm[4] = {vm4.x, vm4.y, vm4.z, vm4.w};
        float vzm[4] = {vzp, vzr[0], vzr[1], vzr[2]};
#pragma unroll
        for (int k = 0; k < 4; ++k) {
            pr[k] = fr[k] * pr[k]
                  - dkxr[k] * (vxr[k] - vxm[k])
                  - dkzr[k] * (vzr[k] - vzm[k])
                  + sfr[k] * wv;
        }
        *(float4*)&sp[jb] = make_float4(pr[0], pr[1], pr[2], pr[3]);
        __syncthreads();

        // ---- receivers: sp stable during next velocity phase ----
        if (rown) out[(s * NTc + t0 + tau) * NRc + tid] = sp[rj];
    }

    // ---- store central 16x16: strips with li in [8,24), lk0 in {8..20} ----
    if (((unsigned)(li - TS) < (unsigned)Bt) &&
        ((unsigned)(lk0 - TS) < (unsigned)Bt)) {
        *(float4*)(p_out  + c4) = make_float4(pr[0], pr[1], pr[2], pr[3]);
        *(float4*)(vx_out + c4) = make_float4(vxr[0], vxr[1], vxr[2], vxr[3]);
        *(float4*)(vz_out + c4) = make_float4(vzr[0], vzr[1], vzr[2], vzr[3]);
    }
}

extern "C" void kernel_launch(void* const* d_in, const int* in_sizes, int n_in,
                              void* d_out, int out_size, void* d_ws, size_t ws_size,
                              hipStream_t stream)
{
    const float* vp      = (const float*)d_in[0];
    const float* rho     = (const float*)d_in[1];
    const float* damp    = (const float*)d_in[2];
    const float* wavelet = (const float*)d_in[3];
    const int*   src_x   = (const int*)d_in[4];
    const int*   src_z   = (const int*)d_in[5];
    const int*   rcv_x   = (const int*)d_in[6];
    const int*   rcv_z   = (const int*)d_in[7];
    float* out = (float*)d_out;
    float* ws  = (float*)d_ws;

    const size_t F = (size_t)NSc * NXZ;
    float* pA  = ws;
    float* vxA = pA  + F;
    float* vzA = vxA + F;
    float* pB  = vzA + F;
    float* vxB = pB  + F;
    float* vzB = vxB + F;

    const int nblk = NSc * (NXc / Bt) * (NZc / Bt);  // 1024
    const int nlaunch = NTc / TS;                    // 50

    for (int l = 0; l < nlaunch; ++l) {
        const float* pi  = (l & 1) ? pB  : pA;
        const float* vxi = (l & 1) ? vxB : vxA;
        const float* vzi = (l & 1) ? vzB : vzA;
        float* po  = (l & 1) ? pA  : pB;
        float* vxo = (l & 1) ? vxA : vxB;
        float* vzo = (l & 1) ? vzA : vzB;
        tstep_kernel<<<nblk, BT, 0, stream>>>(
            pi, vxi, vzi, po, vxo, vzo,
            vp, rho, damp, wavelet, src_x, src_z, rcv_x, rcv_z, out,
            l * TS, (l == 0) ? 1 : 0);
    }
}